// Round 5
// baseline (134.568 us; speedup 1.0000x reference)
//
#include <hip/hip_runtime.h>
#include <stdint.h>

// MaxSimLoss: anchor [256,64,128] f32, pos/neg [256,512,128] f32 -> scalar f32.
// Memory/latency-bound. Barrier-free main loop, fragments loaded straight from
// global in MFMA layout, norms in-register. R3 post-mortem: 4-wave blocks gave
// only 2 waves/SIMD (Occupancy 22%) -> latency-bound at ~4.5 TB/s delivered.
// R4: 8-wave blocks (512 thr), wave owns 64 s-rows -> 4 waves/SIMD.

#define MARGIN_F 0.1f

typedef __attribute__((ext_vector_type(8))) short short8;   // 8 bf16
typedef __attribute__((ext_vector_type(4))) float floatx4;  // 4 f32 acc

// f32 -> bf16 round-to-nearest-even (inputs finite).
__device__ __forceinline__ unsigned short f2bf(float f) {
  union { float f; uint32_t u; } x; x.f = f;
  uint32_t u = x.u;
  return (unsigned short)((u + 0x7FFFu + ((u >> 16) & 1u)) >> 16);
}

__device__ __forceinline__ short8 pack8(float4 a, float4 b) {
  short8 r;
  r[0] = (short)f2bf(a.x); r[1] = (short)f2bf(a.y);
  r[2] = (short)f2bf(a.z); r[3] = (short)f2bf(a.w);
  r[4] = (short)f2bf(b.x); r[5] = (short)f2bf(b.y);
  r[6] = (short)f2bf(b.z); r[7] = (short)f2bf(b.w);
  return r;
}

__device__ __forceinline__ float sq4(float4 a) {
  return a.x * a.x + a.y * a.y + a.z * a.z + a.w * a.w;
}

// One block per (batch, side); 8 waves partition s (64 rows each, 4 chunks).
// Fragment pattern (verified R2/R3): lane holds row (lane&15), elements
// (lane>>4)*8 + k*32 .. +8 per k-slice; identical for A and B -> D = A.B^T
// with row(t) = (lane>>4)*4 + j, col(s) = lane&15.
__global__ __launch_bounds__(512, 4) void maxsim_kernel(
    const float* __restrict__ anchor, const float* __restrict__ pos,
    const float* __restrict__ neg, float* __restrict__ scores) {
  __shared__ float sInvA[64];
  __shared__ float sPart[8][64];

  int bs = blockIdx.x;
  int b = bs >> 1;
  int side = bs & 1;
  const float* base = (side ? neg : pos) + (size_t)b * 512 * 128;
  const float* abase = anchor + (size_t)b * 64 * 128;

  int tid = threadIdx.x;
  int lane = tid & 63;
  int wid = tid >> 6;  // 0..7
  int r = lane & 15;   // fragment row within subtile / accumulator col
  int g = lane >> 4;   // k-group (elements g*8 + k*32)

  const float* sbase = base + (size_t)wid * 64 * 128;

  // Issue chunk-0 s-loads FIRST so their latency hides under the anchor phase.
  float4 buf[2][8];  // fully unrolled chunk loop -> static indexing (rule #20)
  {
    const float* p = sbase + (size_t)r * 128 + g * 8;
#pragma unroll
    for (int k = 0; k < 4; ++k) {
      buf[0][2 * k] = *reinterpret_cast<const float4*>(p + k * 32);
      buf[0][2 * k + 1] = *reinterpret_cast<const float4*>(p + k * 32 + 4);
    }
  }

  // --- A: all 4 t-subtiles into registers, norms in-register. ---
  short8 aF[4][4];
#pragma unroll
  for (int tst = 0; tst < 4; ++tst) {
    const float* arow = abase + (size_t)(tst * 16 + r) * 128 + g * 8;
    float ssa[4];
#pragma unroll
    for (int k = 0; k < 4; ++k) {
      float4 v0 = *reinterpret_cast<const float4*>(arow + k * 32);
      float4 v1 = *reinterpret_cast<const float4*>(arow + k * 32 + 4);
      ssa[k] = sq4(v0) + sq4(v1);
      aF[tst][k] = pack8(v0, v1);
    }
    float ss = (ssa[0] + ssa[1]) + (ssa[2] + ssa[3]);  // tree, short chain
    // 4 lane-groups hold this row's 4 quarters -> 2-shuffle sum.
    ss += __shfl_xor(ss, 16);
    ss += __shfl_xor(ss, 32);
    if (g == 0) sInvA[tst * 16 + r] = 1.0f / fmaxf(sqrtf(ss), 1e-12f);
  }
  __syncthreads();  // sInvA ready; last sync until epilogue

  float rmax[4][4];
#pragma unroll
  for (int tst = 0; tst < 4; ++tst)
#pragma unroll
    for (int j = 0; j < 4; ++j) rmax[tst][j] = -1e30f;

#pragma unroll
  for (int i = 0; i < 4; ++i) {
    int cur = i & 1;
    if (i < 3) {
      const float* p = sbase + (size_t)((i + 1) * 16 + r) * 128 + g * 8;
#pragma unroll
      for (int k = 0; k < 4; ++k) {
        buf[cur ^ 1][2 * k] = *reinterpret_cast<const float4*>(p + k * 32);
        buf[cur ^ 1][2 * k + 1] =
            *reinterpret_cast<const float4*>(p + k * 32 + 4);
      }
    }
    // Row norm for this lane's loaded row (s = wid*64 + i*16 + r).
    float ss = ((sq4(buf[cur][0]) + sq4(buf[cur][1])) +
                (sq4(buf[cur][2]) + sq4(buf[cur][3]))) +
               ((sq4(buf[cur][4]) + sq4(buf[cur][5])) +
                (sq4(buf[cur][6]) + sq4(buf[cur][7])));
    ss += __shfl_xor(ss, 16);
    ss += __shfl_xor(ss, 32);
    float invb = 1.0f / fmaxf(sqrtf(ss), 1e-12f);

    short8 bF[4];
#pragma unroll
    for (int k = 0; k < 4; ++k)
      bF[k] = pack8(buf[cur][2 * k], buf[cur][2 * k + 1]);

    floatx4 acc[4] = {{0.f, 0.f, 0.f, 0.f},
                      {0.f, 0.f, 0.f, 0.f},
                      {0.f, 0.f, 0.f, 0.f},
                      {0.f, 0.f, 0.f, 0.f}};
#pragma unroll
    for (int k = 0; k < 4; ++k)
#pragma unroll
      for (int tst = 0; tst < 4; ++tst)
        acc[tst] = __builtin_amdgcn_mfma_f32_16x16x32_bf16(aF[tst][k], bF[k],
                                                           acc[tst], 0, 0, 0);
    // acc[tst][j]: row t = tst*16 + g*4 + j, col s-rel = lane&15.
    // invb for col r is this lane's own invb (it loaded row i*16 + r).
#pragma unroll
    for (int tst = 0; tst < 4; ++tst)
#pragma unroll
      for (int j = 0; j < 4; ++j)
        rmax[tst][j] = fmaxf(rmax[tst][j], acc[tst][j] * invb);
  }

  // Butterfly-max over cols (lane bits 0-3) -> per-t max over wave's s-range.
#pragma unroll
  for (int tst = 0; tst < 4; ++tst)
#pragma unroll
    for (int j = 0; j < 4; ++j) {
      float m = rmax[tst][j];
      m = fmaxf(m, __shfl_xor(m, 1));
      m = fmaxf(m, __shfl_xor(m, 2));
      m = fmaxf(m, __shfl_xor(m, 4));
      m = fmaxf(m, __shfl_xor(m, 8));
      rmax[tst][j] = m;  // t = tst*16 + g*4 + j, uniform over lane bits 0-3
    }
  if (r == 0) {
#pragma unroll
    for (int tst = 0; tst < 4; ++tst)
#pragma unroll
      for (int j = 0; j < 4; ++j)
        sPart[wid][tst * 16 + g * 4 + j] = rmax[tst][j];
  }
  __syncthreads();
  if (tid < 64) {
    float m = sPart[0][tid];
#pragma unroll
    for (int w = 1; w < 8; ++w) m = fmaxf(m, sPart[w][tid]);
    float val = m * sInvA[tid];
    val += __shfl_xor(val, 1);
    val += __shfl_xor(val, 2);
    val += __shfl_xor(val, 4);
    val += __shfl_xor(val, 8);
    val += __shfl_xor(val, 16);
    val += __shfl_xor(val, 32);
    if (tid == 0) scores[bs] = val * (1.0f / 64.0f);
  }
}

// scores[2b] = pos_score, scores[2b+1] = neg_score. Hinge + mean, one block.
__global__ void hinge_reduce_kernel(const float* __restrict__ scores,
                                    float* __restrict__ out) {
  int tid = threadIdx.x;  // 256 threads, one per batch
  float p = scores[2 * tid];
  float n = scores[2 * tid + 1];
  float h = fmaxf(MARGIN_F + n - p, 0.0f);
  h += __shfl_xor(h, 1);
  h += __shfl_xor(h, 2);
  h += __shfl_xor(h, 4);
  h += __shfl_xor(h, 8);
  h += __shfl_xor(h, 16);
  h += __shfl_xor(h, 32);
  __shared__ float sw[4];
  if ((tid & 63) == 0) sw[tid >> 6] = h;
  __syncthreads();
  if (tid == 0) out[0] = (sw[0] + sw[1] + sw[2] + sw[3]) * (1.0f / 256.0f);
}

extern "C" void kernel_launch(void* const* d_in, const int* in_sizes, int n_in,
                              void* d_out, int out_size, void* d_ws,
                              size_t ws_size, hipStream_t stream) {
  const float* anchor = (const float*)d_in[0];
  const float* pos = (const float*)d_in[1];
  const float* neg = (const float*)d_in[2];
  float* scores = (float*)d_ws;  // 512 floats
  maxsim_kernel<<<dim3(512), dim3(512), 0, stream>>>(anchor, pos, neg, scores);
  hinge_reduce_kernel<<<dim3(1), dim3(256), 0, stream>>>(scores, (float*)d_out);
}